// Round 15
// baseline (152.485 us; speedup 1.0000x reference)
//
#include <hip/hip_runtime.h>
#include <hip/hip_bf16.h>
#include <stdint.h>

// Problem constants
#define BDIM 4096
#define CDIM 10000
#define DDIM 512
#define CPAD 10112  // 79 * 128, padded N so GEMM loads need no guards
#define NT 16       // K tiles (512 / 32)

typedef __bf16 bf16_t;
typedef __attribute__((ext_vector_type(2))) __bf16 bf16x2;
typedef __attribute__((ext_vector_type(8))) __bf16 bf16x8;
typedef __attribute__((ext_vector_type(2))) float f32x2;
typedef __attribute__((ext_vector_type(4))) float f32x4;

__device__ __forceinline__ void gl_lds16(const void* g, void* s) {
  // async global->LDS, 16B per lane; LDS dest = wave-uniform base + lane*16
  __builtin_amdgcn_global_load_lds(
      (const __attribute__((address_space(1))) void*)g,
      (__attribute__((address_space(3))) void*)s, 16, 0, 0);
}

// LDS-only barrier: waits ds ops (lgkmcnt) but lets NT stores keep flying.
__device__ __forceinline__ void lds_barrier() {
  asm volatile("s_waitcnt lgkmcnt(0)" ::: "memory");
  __builtin_amdgcn_s_barrier();
  __builtin_amdgcn_sched_barrier(0);
}

// --- prep, wave-per-row: block = 4 waves = 4 rows; 8 f32/lane (2x f32x4),
// pure shuffle reduction (no LDS, no barrier). Rows [0,BDIM) = feat,
// [BDIM, BDIM+CPAD) = weights (zero-pad >= CDIM).
__global__ __launch_bounds__(256) void prep(
    const float* __restrict__ feat, const float* __restrict__ w,
    bf16_t* __restrict__ fb, bf16_t* __restrict__ wb,
    float* __restrict__ f2, float* __restrict__ w2,
    float* __restrict__ wout) {
  const int t = threadIdx.x;
  const int lane = t & 63;
  const int wv = t >> 6;
  const int r = blockIdx.x * 4 + wv;  // global row index (feat space)
  const int c0 = lane * 8;

  if (r < BDIM) {
    const f32x4 v0 = *(const f32x4*)(feat + (size_t)r * DDIM + c0);
    const f32x4 v1 = *(const f32x4*)(feat + (size_t)r * DDIM + c0 + 4);
    bf16x8 o;
#pragma unroll
    for (int j = 0; j < 4; ++j) {
      o[j] = (__bf16)v0[j];
      o[j + 4] = (__bf16)v1[j];
    }
    *(bf16x8*)(fb + (size_t)r * DDIM + c0) = o;
    float ss = v0.x * v0.x + v0.y * v0.y + v0.z * v0.z + v0.w * v0.w +
               v1.x * v1.x + v1.y * v1.y + v1.z * v1.z + v1.w * v1.w;
#pragma unroll
    for (int off = 32; off > 0; off >>= 1) ss += __shfl_down(ss, off);
    if (lane == 0) f2[r] = ss;
  } else {
    const int row = r - BDIM;  // weight row
    if (row < CDIM) {
      const f32x4 v0 = *(const f32x4*)(w + (size_t)row * DDIM + c0);
      const f32x4 v1 = *(const f32x4*)(w + (size_t)row * DDIM + c0 + 4);
      __builtin_nontemporal_store(v0, (f32x4*)(wout + (size_t)row * DDIM + c0));
      __builtin_nontemporal_store(
          v1, (f32x4*)(wout + (size_t)row * DDIM + c0 + 4));
      bf16x8 o;
#pragma unroll
      for (int j = 0; j < 4; ++j) {
        o[j] = (__bf16)v0[j];
        o[j + 4] = (__bf16)v1[j];
      }
      *(bf16x8*)(wb + (size_t)row * DDIM + c0) = o;
      float ss = v0.x * v0.x + v0.y * v0.y + v0.z * v0.z + v0.w * v0.w +
                 v1.x * v1.x + v1.y * v1.y + v1.z * v1.z + v1.w * v1.w;
#pragma unroll
      for (int off = 32; off > 0; off >>= 1) ss += __shfl_down(ss, off);
      if (lane == 0) w2[row] = ss;
    } else if (row < CPAD) {
      bf16x8 z = {};
      *(bf16x8*)(wb + (size_t)row * DDIM + c0) = z;
      if (lane == 0) w2[row] = 0.0f;
    }
  }
}

// --- main GEMM + RBF epilogue ---
// R12 structure (best: 106.8 µs) at 5 BLOCKS/CU: 128x128 tile, BK=32,
// 4 waves (2x2), operand-swapped mfma, 2-buffer 2-phase K-loop,
// barrier-free wave-private LDS-slab epilogue with dual NT stores.
// R15 single variable: occupancy 4 -> 5 blocks/CU. LDS = exactly 32768 B
// (f2/w2 in registers, not LDS); __launch_bounds__(256,5) -> VGPR <= 102;
// VGPR diet: single af fragment per mi (wf[4] persistent), no setprio,
// K-offsets folded into global_load_lds immediates.
__global__ __launch_bounds__(256, 5) void rbf_gemm(
    const bf16_t* __restrict__ A,   // [4096][512] bf16  (feat)
    const bf16_t* __restrict__ Bw,  // [10112][512] bf16 (weights, padded)
    const float* __restrict__ f2g, const float* __restrict__ w2g,
    float* __restrict__ out) {
  // pool: K-loop = 2 x [A(8KB) B(8KB)]; epilogue = 4 x 8KB wave slabs
  __shared__ __align__(16) char pool[32768];
  bf16_t* Pb = (bf16_t*)pool;  // buf b: A @ b*8192, B @ b*8192+4096 (elems)

  // 1-D grid, bijective XCD swizzle (nwg = 2528 = 8*316), bm fastest
  // (R5/R6 A/B: bm-fastest wins — concurrent blocks share the B-tile).
  const int bid = blockIdx.x;
  const int wg = (bid & 7) * (2528 / 8) + (bid >> 3);
  const int bm = wg & 31;  // 0..31 (M tiles) -- fastest within XCD chunk
  const int bn = wg >> 5;  // 0..78 (N tiles)
  const int t = threadIdx.x;
  const int lane = t & 63;

  const int wv = t >> 6;
  const int wm = (wv >> 1) * 64;  // feat group of this wave
  const int wn = (wv & 1) * 64;   // weight group of this wave
  const int fr = lane & 15;
  const int k8 = (lane >> 4) * 8;
  const int g16 = lane >> 4;  // 0..3

  // f2 rows for this thread's fragments (4 VGPR; replaces f2s LDS)
  float f2r[4];
#pragma unroll
  for (int mi = 0; mi < 4; ++mi)
    f2r[mi] = f2g[bm * 128 + wm + mi * 16 + fr];

  // staging addressing: 4 threads x 16B per 32-elem row; 64 rows per call
  const int sr = t >> 2;
  const int sc = (t & 3) * 8;
  const bf16_t* ga0 = A + (size_t)(bm * 128 + sr) * DDIM + sc;
  const bf16_t* ga1 = ga0 + (size_t)64 * DDIM;
  const bf16_t* gb0 = Bw + (size_t)(bn * 128 + sr) * DDIM + sc;
  const bf16_t* gb1 = gb0 + (size_t)64 * DDIM;

#define STAGE(b, kt)                                \
  do {                                              \
    const int k0_ = (kt) * 32;                      \
    bf16_t* Ab_ = Pb + (b) * 8192;                  \
    gl_lds16(ga0 + k0_, Ab_ + t * 8);               \
    gl_lds16(ga1 + k0_, Ab_ + 2048 + t * 8);        \
    gl_lds16(gb0 + k0_, Ab_ + 4096 + t * 8);        \
    gl_lds16(gb1 + k0_, Ab_ + 4096 + 2048 + t * 8); \
  } while (0)

  f32x4 acc[4][4];
#pragma unroll
  for (int i = 0; i < 4; ++i)
#pragma unroll
    for (int j = 0; j < 4; ++j) acc[i][j] = (f32x4){0.f, 0.f, 0.f, 0.f};

  STAGE(0, 0);
  __syncthreads();  // drains tile 0 (f2r loads complete independently)

#pragma unroll
  for (int kt = 0; kt < NT; ++kt) {
    const int cur = kt & 1;
    if (kt + 1 < NT) STAGE(cur ^ 1, kt + 1);  // issue next-tile loads FIRST
    const bf16_t* Ab = Pb + cur * 8192;
    bf16x8 wf[4];
#pragma unroll
    for (int ni = 0; ni < 4; ++ni)
      wf[ni] = *(const bf16x8*)(Ab + 4096 + (wn + ni * 16 + fr) * 32 + k8);
#pragma unroll
    for (int mi = 0; mi < 4; ++mi) {
      const bf16x8 af = *(const bf16x8*)(Ab + (wm + mi * 16 + fr) * 32 + k8);
#pragma unroll
      for (int ni = 0; ni < 4; ++ni)
        acc[mi][ni] = __builtin_amdgcn_mfma_f32_16x16x32_bf16(
            wf[ni], af, acc[mi][ni], 0, 0, 0);  // swapped: D = W x F^T
    }
    if (kt + 1 < NT) __syncthreads();  // next buf landed; cur safe to reuse
  }

  // all waves past their kt=15 ds_reads before slab reuse
  lds_barrier();

  // Barrier-free wave-private epilogue (R12). Slab: 2 x [16][64] f32
  // (8 KB/wave). Swizzle q=(g+r)&15 -> 2-way max on ds_write and ds_read.
  // w2 from global (L2-hot 40 KB table) -> 16 VGPR, af/wf dead by now.
  float* slab = (float*)pool + wv * 2048;
  const size_t BC = (size_t)BDIM * CDIM;
  const int c_l = g16 * 4;

  f32x4 w2v[4];
#pragma unroll
  for (int ni = 0; ni < 4; ++ni)
    w2v[ni] = *(const f32x4*)(w2g + bn * 128 + wn + ni * 16 + c_l);

#pragma unroll
  for (int mi = 0; mi < 4; ++mi) {
    float* sb = slab + (mi & 1) * 1024;
    const float frow = f2r[mi];
    // fill: lane (fr, g16) covers row fr, col-groups g = ni*4+g16
#pragma unroll
    for (int ni = 0; ni < 4; ++ni) {
      f32x4 st;
#pragma unroll
      for (int j = 0; j < 4; ++j) {
        float m = frow + w2v[ni][j] - 2.0f * acc[mi][ni][j];
        m = fmaxf(m, 0.0f);
        st[j] = __expf(-0.01f * m);
      }
      const int g = ni * 4 + g16;
      const int q = (g + fr) & 15;
      *(f32x4*)&sb[fr * 64 + q * 4] = st;
    }
    // drain: 4 rows/instr (r = s*4+g16), 16 lanes x 16 B = 256 B/row chunk
#pragma unroll
    for (int s = 0; s < 4; ++s) {
      const int r = s * 4 + g16;
      const int g2 = lane & 15;
      const int q2 = (g2 + r) & 15;
      const f32x4 v = *(const f32x4*)&sb[r * 64 + q2 * 4];
      const int gcol = bn * 128 + wn + g2 * 4;
      if (gcol < CDIM) {
        float* p = out + (size_t)(bm * 128 + wm + mi * 16 + r) * CDIM + gcol;
        __builtin_nontemporal_store(v, (f32x4*)p);
        __builtin_nontemporal_store(v, (f32x4*)(p + BC));
      }
    }
  }
#undef STAGE
}

extern "C" void kernel_launch(void* const* d_in, const int* in_sizes, int n_in,
                              void* d_out, int out_size, void* d_ws,
                              size_t ws_size, hipStream_t stream) {
  const float* feat = (const float*)d_in[0];
  // d_in[1] = label (int64) — unused by the reference math
  const float* w = (const float*)d_in[2];
  float* out = (float*)d_out;

  char* ws = (char*)d_ws;
  bf16_t* fb = (bf16_t*)ws;                        // 4096*512*2  = 4,194,304 B
  bf16_t* wb = (bf16_t*)(ws + 4194304);            // 10112*512*2 = 10,354,688 B
  float* f2 = (float*)(ws + 4194304 + 10354688);   // 16,384 B
  float* w2 = (float*)(ws + 4194304 + 10354688 + 16384);  // 40,448 B

  float* wout = out + (size_t)2 * BDIM * CDIM;  // weights passthrough segment

  prep<<<(BDIM + CPAD) / 4, 256, 0, stream>>>(feat, w, fb, wb, f2, w2, wout);
  rbf_gemm<<<2528, 256, 0, stream>>>(fb, wb, f2, w2, out);
}

// Round 16
// 106.291 us; speedup vs baseline: 1.4346x; 1.4346x over previous
//
#include <hip/hip_runtime.h>
#include <hip/hip_bf16.h>
#include <stdint.h>

// Problem constants
#define BDIM 4096
#define CDIM 10000
#define DDIM 512
#define CPAD 10112  // 79 * 128, padded N so GEMM loads need no guards
#define NT 16       // K tiles (512 / 32)

typedef __bf16 bf16_t;
typedef __attribute__((ext_vector_type(2))) __bf16 bf16x2;
typedef __attribute__((ext_vector_type(8))) __bf16 bf16x8;
typedef __attribute__((ext_vector_type(2))) float f32x2;
typedef __attribute__((ext_vector_type(4))) float f32x4;

__device__ __forceinline__ void gl_lds16(const void* g, void* s) {
  // async global->LDS, 16B per lane; LDS dest = wave-uniform base + lane*16
  __builtin_amdgcn_global_load_lds(
      (const __attribute__((address_space(1))) void*)g,
      (__attribute__((address_space(3))) void*)s, 16, 0, 0);
}

// LDS-only barrier: waits ds ops (lgkmcnt) but lets NT stores keep flying.
__device__ __forceinline__ void lds_barrier() {
  asm volatile("s_waitcnt lgkmcnt(0)" ::: "memory");
  __builtin_amdgcn_s_barrier();
  __builtin_amdgcn_sched_barrier(0);
}

// --- fused prep: rows [0,BDIM) = feat, rows [BDIM,BDIM+CPAD) = weights ---
__global__ __launch_bounds__(256) void prep(
    const float* __restrict__ feat, const float* __restrict__ w,
    bf16_t* __restrict__ fb, bf16_t* __restrict__ wb,
    float* __restrict__ f2, float* __restrict__ w2,
    float* __restrict__ wout) {
  const int b = blockIdx.x;
  const int t = threadIdx.x;
  __shared__ float red[4];
  if (b < BDIM) {
    const f32x2 v = ((const f32x2*)(feat + (size_t)b * DDIM))[t];
    bf16x2 o;
    o.x = (__bf16)v.x;
    o.y = (__bf16)v.y;
    ((bf16x2*)fb)[(size_t)b * (DDIM / 2) + t] = o;
    float ss = v.x * v.x + v.y * v.y;
#pragma unroll
    for (int off = 32; off > 0; off >>= 1) ss += __shfl_down(ss, off);
    if ((t & 63) == 0) red[t >> 6] = ss;
    __syncthreads();
    if (t == 0) f2[b] = red[0] + red[1] + red[2] + red[3];
  } else {
    const int row = b - BDIM;
    if (row < CDIM) {
      const f32x2 v = ((const f32x2*)(w + (size_t)row * DDIM))[t];
      __builtin_nontemporal_store(v, (f32x2*)(wout + (size_t)row * DDIM) + t);
      bf16x2 o;
      o.x = (__bf16)v.x;
      o.y = (__bf16)v.y;
      ((bf16x2*)wb)[(size_t)row * (DDIM / 2) + t] = o;
      float ss = v.x * v.x + v.y * v.y;
#pragma unroll
      for (int off = 32; off > 0; off >>= 1) ss += __shfl_down(ss, off);
      if ((t & 63) == 0) red[t >> 6] = ss;
      __syncthreads();
      if (t == 0) w2[row] = red[0] + red[1] + red[2] + red[3];
    } else {
      bf16x2 z;
      z.x = (__bf16)0.0f;
      z.y = (__bf16)0.0f;
      ((bf16x2*)wb)[(size_t)row * (DDIM / 2) + t] = z;
      if (t == 0) w2[row] = 0.0f;
    }
  }
}

// --- main GEMM + RBF epilogue ---
// R12 configuration (best measured: 106.8 µs): 128x128 tile, BK=32,
// 4 waves (2x2), operand-swapped mfma, 2-buffer LDS (32 KB) 2-phase loop,
// 4 blocks/CU, barrier-free wave-private LDS-slab epilogue, dual NT stores.
__global__ __launch_bounds__(256, 4) void rbf_gemm(
    const bf16_t* __restrict__ A,   // [4096][512] bf16  (feat)
    const bf16_t* __restrict__ Bw,  // [10112][512] bf16 (weights, padded)
    const float* __restrict__ f2g, const float* __restrict__ w2g,
    float* __restrict__ out) {
  // pool: K-loop = 2 x [A(8KB) B(8KB)]; epilogue = 4 x 8KB wave slabs
  __shared__ __align__(16) char pool[32768];
  bf16_t* Pb = (bf16_t*)pool;  // buf b: A @ b*8192, B @ b*8192+4096 (elems)
  __shared__ float f2s[128];
  __shared__ float w2s[128];

  // 1-D grid, bijective XCD swizzle (nwg = 2528 = 8*316), bm fastest
  // (R5/R6 A/B: bm-fastest wins — concurrent blocks share the B-tile).
  const int bid = blockIdx.x;
  const int wg = (bid & 7) * (2528 / 8) + (bid >> 3);
  const int bm = wg & 31;  // 0..31 (M tiles) -- fastest within XCD chunk
  const int bn = wg >> 5;  // 0..78 (N tiles)
  const int t = threadIdx.x;
  const int lane = t & 63;

  if (t < 128)
    f2s[t] = f2g[bm * 128 + t];
  else
    w2s[t - 128] = w2g[bn * 128 + (t - 128)];

  // staging addressing: 4 threads x 16B per 32-elem row; 64 rows per call
  const int sr = t >> 2;
  const int sc = (t & 3) * 8;
  const bf16_t* ga0 = A + (size_t)(bm * 128 + sr) * DDIM + sc;
  const bf16_t* ga1 = ga0 + (size_t)64 * DDIM;
  const bf16_t* gb0 = Bw + (size_t)(bn * 128 + sr) * DDIM + sc;
  const bf16_t* gb1 = gb0 + (size_t)64 * DDIM;

  const int wv = t >> 6;
  const int wm = (wv >> 1) * 64;  // feat group of this wave
  const int wn = (wv & 1) * 64;   // weight group of this wave
  const int fr = lane & 15;
  const int k8 = (lane >> 4) * 8;
  const int g16 = lane >> 4;  // 0..3

#define STAGE(b, kt)                                \
  do {                                              \
    const int k0_ = (kt) * 32;                      \
    bf16_t* Ab_ = Pb + (b) * 8192;                  \
    gl_lds16(ga0 + k0_, Ab_ + t * 8);               \
    gl_lds16(ga1 + k0_, Ab_ + 2048 + t * 8);        \
    gl_lds16(gb0 + k0_, Ab_ + 4096 + t * 8);        \
    gl_lds16(gb1 + k0_, Ab_ + 4096 + 2048 + t * 8); \
  } while (0)

  f32x4 acc[4][4];
#pragma unroll
  for (int i = 0; i < 4; ++i)
#pragma unroll
    for (int j = 0; j < 4; ++j) acc[i][j] = (f32x4){0.f, 0.f, 0.f, 0.f};

  STAGE(0, 0);
  __syncthreads();  // drains tile 0 + f2s/w2s

#pragma unroll
  for (int kt = 0; kt < NT; ++kt) {
    const int cur = kt & 1;
    if (kt + 1 < NT) STAGE(cur ^ 1, kt + 1);  // issue next-tile loads FIRST
    const bf16_t* Ab = Pb + cur * 8192;
    bf16x8 af[4], wf[4];
#pragma unroll
    for (int mi = 0; mi < 4; ++mi)
      af[mi] = *(const bf16x8*)(Ab + (wm + mi * 16 + fr) * 32 + k8);
#pragma unroll
    for (int ni = 0; ni < 4; ++ni)
      wf[ni] = *(const bf16x8*)(Ab + 4096 + (wn + ni * 16 + fr) * 32 + k8);
    __builtin_amdgcn_s_setprio(1);
#pragma unroll
    for (int mi = 0; mi < 4; ++mi)
#pragma unroll
      for (int ni = 0; ni < 4; ++ni)
        acc[mi][ni] = __builtin_amdgcn_mfma_f32_16x16x32_bf16(
            wf[ni], af[mi], acc[mi][ni], 0, 0, 0);  // swapped: D = W x F^T
    __builtin_amdgcn_s_setprio(0);
    if (kt + 1 < NT) __syncthreads();  // next buf landed; cur safe to reuse
  }

  // all waves past their kt=15 ds_reads before slab reuse (no vmcnt pending:
  // kt=14's STAGE drained at its __syncthreads; kt=15 staged nothing)
  lds_barrier();

  // Barrier-free wave-private epilogue. Slab: 2 x [16][64] f32 (8 KB/wave).
  // Swizzle: col-group g (f32x4) at row r lives at q=(g+r)&15 -> 2-way max
  // on both ds_write and ds_read. Same-wave DS ops are in-order (WAR safe).
  float* slab = (float*)pool + wv * 2048;
  const size_t BC = (size_t)BDIM * CDIM;
  const int c_l = g16 * 4;

#pragma unroll
  for (int mi = 0; mi < 4; ++mi) {
    float* sb = slab + (mi & 1) * 1024;
    const float frow = f2s[wm + mi * 16 + fr];
    // fill: lane (fr, g16) covers row fr, col-groups g = ni*4+g16
#pragma unroll
    for (int ni = 0; ni < 4; ++ni) {
      const int cl = wn + ni * 16 + c_l;
      f32x4 st;
#pragma unroll
      for (int j = 0; j < 4; ++j) {
        float m = frow + w2s[cl + j] - 2.0f * acc[mi][ni][j];
        m = fmaxf(m, 0.0f);
        st[j] = __expf(-0.01f * m);
      }
      const int g = ni * 4 + g16;
      const int q = (g + fr) & 15;
      *(f32x4*)&sb[fr * 64 + q * 4] = st;
    }
    // drain: 4 rows/instr (r = s*4+g16), 16 lanes x 16 B = 256 B/row chunk
#pragma unroll
    for (int s = 0; s < 4; ++s) {
      const int r = s * 4 + g16;
      const int g2 = lane & 15;
      const int q2 = (g2 + r) & 15;
      const f32x4 v = *(const f32x4*)&sb[r * 64 + q2 * 4];
      const int gcol = bn * 128 + wn + g2 * 4;
      if (gcol < CDIM) {
        float* p = out + (size_t)(bm * 128 + wm + mi * 16 + r) * CDIM + gcol;
        __builtin_nontemporal_store(v, (f32x4*)p);
        __builtin_nontemporal_store(v, (f32x4*)(p + BC));
      }
    }
  }
#undef STAGE
}

extern "C" void kernel_launch(void* const* d_in, const int* in_sizes, int n_in,
                              void* d_out, int out_size, void* d_ws,
                              size_t ws_size, hipStream_t stream) {
  const float* feat = (const float*)d_in[0];
  // d_in[1] = label (int64) — unused by the reference math
  const float* w = (const float*)d_in[2];
  float* out = (float*)d_out;

  char* ws = (char*)d_ws;
  bf16_t* fb = (bf16_t*)ws;                        // 4096*512*2  = 4,194,304 B
  bf16_t* wb = (bf16_t*)(ws + 4194304);            // 10112*512*2 = 10,354,688 B
  float* f2 = (float*)(ws + 4194304 + 10354688);   // 16,384 B
  float* w2 = (float*)(ws + 4194304 + 10354688 + 16384);  // 40,448 B

  float* wout = out + (size_t)2 * BDIM * CDIM;  // weights passthrough segment

  prep<<<BDIM + CPAD, 256, 0, stream>>>(feat, w, fb, wb, f2, w2, wout);
  rbf_gemm<<<2528, 256, 0, stream>>>(fb, wb, f2, w2, out);
}